// Round 5
// baseline (201.923 us; speedup 1.0000x reference)
//
#include <hip/hip_runtime.h>
#include <cstdint>

typedef unsigned short u16;
typedef __bf16 bf16;
typedef bf16 bf16x8 __attribute__((ext_vector_type(8)));
typedef u16 u16x4 __attribute__((ext_vector_type(4)));
typedef u16 u16x8 __attribute__((ext_vector_type(8)));
typedef float f32x4 __attribute__((ext_vector_type(4)));

__device__ __forceinline__ u16 f2b(float f) {
    return __builtin_bit_cast(u16, (bf16)f);
}
__device__ __forceinline__ float b2f(u16 u) {
    return __uint_as_float(((unsigned)u) << 16);
}
__device__ __forceinline__ void load_lds16(const void* g, void* l) {
    auto gp = reinterpret_cast<const __attribute__((address_space(1))) void*>(
        reinterpret_cast<uintptr_t>(g));
    auto lp = reinterpret_cast<__attribute__((address_space(3))) void*>(
        reinterpret_cast<uintptr_t>(l));
    __builtin_amdgcn_global_load_lds(gp, lp, 16, 0, 0);
}
__device__ __forceinline__ f32x4 mfma16(bf16x8 a, bf16x8 b, f32x4 c) {
    return __builtin_amdgcn_mfma_f32_16x16x32_bf16(a, b, c, 0, 0, 0);
}

// ---------------------------------------------------------------- convert x -> bf16
__global__ __launch_bounds__(256) void convx_kernel(const float* __restrict__ x,
                                                    u16* __restrict__ xb, int n4) {
    int i = blockIdx.x * blockDim.x + threadIdx.x;
    int stride = gridDim.x * blockDim.x;
    for (; i < n4; i += stride) {
        float4 v = ((const float4*)x)[i];
        u16x4 r;
        r[0] = f2b(v.x); r[1] = f2b(v.y); r[2] = f2b(v.z); r[3] = f2b(v.w);
        *(u16x4*)&xb[(size_t)i * 4] = r;
    }
}

// ------------------- combined transpose+convert for both weights: [K=768][N] f32 -> [N][768] bf16
__global__ __launch_bounds__(256) void wtrans2_kernel(const float* __restrict__ wa,
                                                      const float* __restrict__ wp,
                                                      u16* __restrict__ wTa,
                                                      u16* __restrict__ wTp) {
    __shared__ float tile[32][33];
    const int bx = blockIdx.x;
    const float* w;
    u16* wT;
    int N, n0;
    if (bx < 72) { w = wa; wT = wTa; N = 2304; n0 = bx * 32; }
    else         { w = wp; wT = wTp; N = 768;  n0 = (bx - 72) * 32; }
    const int K = 768;
    int tx = threadIdx.x, ty = threadIdx.y;  // (32, 8)
    int k0 = blockIdx.y * 32;
#pragma unroll
    for (int i = 0; i < 4; ++i)
        tile[ty + i * 8][tx] = w[(size_t)(k0 + ty + i * 8) * N + n0 + tx];
    __syncthreads();
#pragma unroll
    for (int i = 0; i < 4; ++i)
        wT[(size_t)(n0 + ty + i * 8) * K + k0 + tx] = f2b(tile[tx][ty + i * 8]);
}

// ---------------------------------------------------------------- GEMM: C[M][N] = A[M][K] * Bt[N][K]^T + bias
// 128x128 tile, 4 waves, 16x16x32 MFMA, gload_lds staging, XCD-aware block swizzle.
template <bool OUT_BF16>
__global__ __launch_bounds__(256, 3) void gemm_kernel(const u16* __restrict__ A,
                                                      const u16* __restrict__ Bt,
                                                      const float* __restrict__ bias,
                                                      void* __restrict__ out,
                                                      int M, int N, int K) {
    __shared__ __align__(16) u16 As[128 * 64];
    __shared__ __align__(16) u16 Bs[128 * 64];
    const int tid = threadIdx.x;
    const int wave = tid >> 6, lane = tid & 63;
    const int l15 = lane & 15, lg = lane >> 4;
    // XCD-aware swizzle (T1); nwg % 8 == 0 for both GEMMs here.
    const int gx = gridDim.x;
    const int nwg = gx * gridDim.y;
    const int lin = blockIdx.y * gx + blockIdx.x;
    const int swz = (lin & 7) * (nwg >> 3) + (lin >> 3);
    const int tm = (swz / gx) * 128, tn = (swz % gx) * 128;
    const int wr = (wave >> 1) * 64, wc = (wave & 1) * 64;

    f32x4 acc[4][4] = {};

    const int rbase = wave * 8 + (lane >> 3);
    const int sslot = (lane & 7) ^ (rbase & 7);
    const u16* gA = A + (size_t)(tm + rbase) * K + sslot * 8;
    const u16* gB = Bt + (size_t)(tn + rbase) * K + sslot * 8;
    u16* ldsA = As + (size_t)(wave * 8) * 64;
    u16* ldsB = Bs + (size_t)(wave * 8) * 64;

    for (int kt = 0; kt < K; kt += 64) {
#pragma unroll
        for (int i = 0; i < 4; ++i) {
            load_lds16(gA + (size_t)i * 32 * K + kt, ldsA + i * 32 * 64);
            load_lds16(gB + (size_t)i * 32 * K + kt, ldsB + i * 32 * 64);
        }
        __syncthreads();
#pragma unroll
        for (int kk = 0; kk < 64; kk += 32) {
            const int sb = kk >> 3;
            bf16x8 af[4], bfr[4];
#pragma unroll
            for (int m = 0; m < 4; ++m) {
                int row = wr + m * 16 + l15;
                af[m] = *(const bf16x8*)&As[row * 64 + (((sb + lg) ^ (row & 7))) * 8];
            }
#pragma unroll
            for (int n = 0; n < 4; ++n) {
                int row = wc + n * 16 + l15;
                bfr[n] = *(const bf16x8*)&Bs[row * 64 + (((sb + lg) ^ (row & 7))) * 8];
            }
#pragma unroll
            for (int m = 0; m < 4; ++m)
#pragma unroll
                for (int n = 0; n < 4; ++n)
                    acc[m][n] = mfma16(af[m], bfr[n], acc[m][n]);
        }
        __syncthreads();
    }

#pragma unroll
    for (int n = 0; n < 4; ++n) {
        int col = tn + wc + n * 16 + l15;
        float bv = bias[col];
#pragma unroll
        for (int m = 0; m < 4; ++m) {
            int row0 = tm + wr + m * 16 + lg * 4;
#pragma unroll
            for (int r = 0; r < 4; ++r) {
                float v = acc[m][n][r] + bv;
                if constexpr (OUT_BF16)
                    ((u16*)out)[(size_t)(row0 + r) * N + col] = f2b(v);
                else
                    ((float*)out)[(size_t)(row0 + r) * N + col] = v;
            }
        }
    }
}

// ---------------------------------------------------------------- V transpose + fused per-64-tile colsum
// qkv V-part -> vt[bh][d=64][s=2048]; ts_raw[bh][st][d] = sum_s V[st*64+s][d]
__global__ __launch_bounds__(256) void vtrans_kernel(const u16* __restrict__ qkv,
                                                     u16* __restrict__ vt,
                                                     float* __restrict__ ts_raw) {
    __shared__ __align__(16) u16 tile[64][72];
    __shared__ float red2[64][4];
    const int st = blockIdx.x, bh = blockIdx.y;
    const int b = bh / 12, h = bh % 12;
    const int t = threadIdx.x;
    const int sr = t >> 2, c4 = (t & 3) * 16;
    const u16* src = qkv + (size_t)(b * 2048 + st * 64 + sr) * 2304 + 1536 + h * 64 + c4;
    *(u16x8*)&tile[sr][c4] = *(const u16x8*)src;
    *(u16x8*)&tile[sr][c4 + 8] = *(const u16x8*)(src + 8);
    __syncthreads();
    const int dr = t >> 2, s4 = (t & 3) * 16;
    u16x8 w0, w1;
    float psum = 0.f;
#pragma unroll
    for (int j = 0; j < 8; ++j) {
        w0[j] = tile[s4 + j][dr];
        w1[j] = tile[s4 + 8 + j][dr];
        psum += b2f(w0[j]) + b2f(w1[j]);
    }
    u16* dst = vt + ((size_t)bh * 64 + dr) * 2048 + st * 64 + s4;
    *(u16x8*)dst = w0;
    *(u16x8*)(dst + 8) = w1;
    red2[dr][t & 3] = psum;
    __syncthreads();
    if (t < 64)
        ts_raw[((size_t)bh * 32 + st) * 64 + t] =
            red2[t][0] + red2[t][1] + red2[t][2] + red2[t][3];
}

// ---------------------------------------------------------------- attention
// Swapped-operand flash, QBLK=64, KBLK=64, defer-max, K-row permutation so the
// softmax'd P is ALREADY in PV's B-fragment register layout (no P LDS round-trip).
// sigma(rho) = ((rho&0x1C)<<1) | ((rho>>5)<<2) | (rho&3): LDS row rho holds K row sigma(rho);
// then lane's QK output p[n][r] = P[k=(n&1)*32+lg*8+(n>>1)*4+r][q=l15] and PV's
// B-operand for k-slice ks is bp_ks[j] = p[2*(j>>2)+ks][j&3] -- register relabel only.
__global__ __launch_bounds__(256, 5) void attn_kernel(const u16* __restrict__ qkv,
                                                      const u16* __restrict__ vt,
                                                      const float* __restrict__ ts_raw,
                                                      u16* __restrict__ aout) {
    __shared__ __align__(16) u16 Ks[2][64 * 64];
    __shared__ __align__(16) u16 Vs[2][64 * 64];   // transposed V: [d][k], true-k columns
    const int bh = blockIdx.x;                     // bh fastest: same-bh blocks share XCD L2
    const int qt = 31 - blockIdx.y;                // longest-first dispatch
    const int b = bh / 12, h = bh % 12;
    const int tid = threadIdx.x, wave = tid >> 6, lane = tid & 63;
    const int l15 = lane & 15, lg = lane >> 4;
    const int q0 = qt * 64 + wave * 16;
    const size_t rowbase = (size_t)b * 2048;

    // Q fragment (B-operand): lane holds Q[q0+l15][ks*32 + lg*8 .. +8]
    bf16x8 qf[2];
#pragma unroll
    for (int ks = 0; ks < 2; ++ks)
        qf[ks] = *(const bf16x8*)(qkv + (rowbase + q0 + l15) * 2304 + h * 64 +
                                  ks * 32 + lg * 8);

    f32x4 o[4] = {};          // O^T: lane holds O[q=q0+l15][d = dn*16 + lg*4 + r]
    float mrun = -1e30f;
    float lrun = 0.f;         // per-lane partial; folded across lane-groups after loop

    // staging constants (gload_lds: linear LDS dest, pre-swizzled global source)
    const int rbase = wave * 8 + (lane >> 3);
    const int sslot = (lane & 7) ^ (rbase & 7);
    const int sig0 = ((rbase & 0x1C) << 1) | (rbase & 3);   // K-row permutation base
    const u16* gK = qkv + (rowbase + sig0) * 2304 + 768 + h * 64 + sslot * 8;
    const u16* gV = vt + ((size_t)bh * 64 + rbase) * 2048 + sslot * 8;
    const int ldsoff = wave * 8 * 64;

    const int nkt = qt + 1;
    // prologue: stage kt=0 into buffer 0 (K rows permuted: inst i covers sig0 + i*4)
#pragma unroll
    for (int i = 0; i < 2; ++i) {
        load_lds16(gK + (size_t)(i * 4) * 2304, &Ks[0][ldsoff + i * 32 * 64]);
        load_lds16(gV + (size_t)(i * 32) * 2048, &Vs[0][ldsoff + i * 32 * 64]);
    }

    for (int kt = 0; kt < nkt; ++kt) {
        __syncthreads();  // drains vmcnt: tile[cur] ready; prev-iter LDS reads done
        const int cur = kt & 1;
        if (kt + 1 < nkt) {
            const int nx = cur ^ 1;
#pragma unroll
            for (int i = 0; i < 2; ++i) {
                load_lds16(gK + (size_t)((kt + 1) * 64 + i * 4) * 2304,
                           &Ks[nx][ldsoff + i * 32 * 64]);
                load_lds16(gV + (size_t)(i * 32) * 2048 + (kt + 1) * 64,
                           &Vs[nx][ldsoff + i * 32 * 64]);
            }
        }

        // S^T = K Q^T (K rows permuted by sigma)
        f32x4 sacc[4] = {};
        __builtin_amdgcn_s_setprio(1);
#pragma unroll
        for (int ks = 0; ks < 2; ++ks) {
#pragma unroll
            for (int n = 0; n < 4; ++n) {
                int row = n * 16 + l15;
                bf16x8 ak = *(const bf16x8*)&Ks[cur][row * 64 +
                                                     (((ks * 4 + lg) ^ (row & 7))) * 8];
                sacc[n] = mfma16(ak, qf[ks], sacc[n]);
            }
        }
        __builtin_amdgcn_s_setprio(0);

        // reference mask trick on the diagonal tile (true k via sigma)
        if (kt == qt) {
            const int q = q0 + l15;
            const int kb = kt * 64 + lg * 8;
#pragma unroll
            for (int n = 0; n < 4; ++n) {
                const int kn = kb + (n & 1) * 32 + ((n >> 1) << 2);
#pragma unroll
                for (int r = 0; r < 4; ++r)
                    if (kn + r > q) sacc[n][r] = 1e-9f;
            }
        }

        // defer-max: lane-local max; rescale only when it grows >THR
        float mx = fmaxf(fmaxf(sacc[0][0], sacc[0][1]), fmaxf(sacc[0][2], sacc[0][3]));
#pragma unroll
        for (int n = 1; n < 4; ++n)
            mx = fmaxf(mx, fmaxf(fmaxf(sacc[n][0], sacc[n][1]),
                                 fmaxf(sacc[n][2], sacc[n][3])));
        if (__any(mx > mrun + 8.0f)) {
            float rm = fmaxf(mx, __shfl_xor(mx, 16));
            rm = fmaxf(rm, __shfl_xor(rm, 32));
            const float mnew = fmaxf(mrun, rm);
            const float alpha = __expf(mrun - mnew);
            mrun = mnew;
            lrun *= alpha;
#pragma unroll
            for (int dn = 0; dn < 4; ++dn) o[dn] *= alpha;
        }

        // exp (bounded by e^8) and pack straight into PV B-fragments (lane-local!)
#pragma unroll
        for (int n = 0; n < 4; ++n)
#pragma unroll
            for (int r = 0; r < 4; ++r) {
                float p = __expf(sacc[n][r] - mrun);
                lrun += p;
                sacc[n][r] = p;
            }
        bf16x8 bp0, bp1;
#pragma unroll
        for (int j = 0; j < 4; ++j) {
            bp0[j]     = (bf16)sacc[0][j];
            bp0[j + 4] = (bf16)sacc[2][j];
            bp1[j]     = (bf16)sacc[1][j];
            bp1[j + 4] = (bf16)sacc[3][j];
        }

        // O^T += V^T P^T
        __builtin_amdgcn_s_setprio(1);
#pragma unroll
        for (int ks = 0; ks < 2; ++ks) {
            bf16x8 bp = ks ? bp1 : bp0;
#pragma unroll
            for (int dn = 0; dn < 4; ++dn) {
                int row = dn * 16 + l15;
                bf16x8 av = *(const bf16x8*)&Vs[cur][row * 64 +
                                                     (((ks * 4 + lg) ^ (row & 7))) * 8];
                o[dn] = mfma16(av, bp, o[dn]);
            }
        }
        __builtin_amdgcn_s_setprio(0);
    }

    // fold per-lane l across the 4 lane-groups of this row (once, not per tile)
    lrun += __shfl_xor(lrun, 16);
    lrun += __shfl_xor(lrun, 32);

    // analytic future tail: all k >= (qt+1)*64 carry score exactly 1e-9
    if (qt < 31) {
        const float nf = (float)((31 - qt) * 64);
        const float mnew = fmaxf(mrun, 1e-9f);
        const float a = __expf(mrun - mnew);
        const float c = __expf(1e-9f - mnew);
        lrun = lrun * a + nf * c;
        f32x4 suf[4] = {};
        for (int t = qt + 1; t < 32; ++t) {
            const float* sp = ts_raw + ((size_t)bh * 32 + t) * 64;
#pragma unroll
            for (int dn = 0; dn < 4; ++dn)
                suf[dn] += *(const f32x4*)&sp[dn * 16 + lg * 4];
        }
#pragma unroll
        for (int dn = 0; dn < 4; ++dn)
            o[dn] = o[dn] * a + suf[dn] * c;
    }

    // normalize + store merged-head layout [B*S][768] bf16
    const float inv = 1.f / lrun;
    const size_t row = rowbase + q0 + l15;
#pragma unroll
    for (int dn = 0; dn < 4; ++dn) {
        u16x4 st;
#pragma unroll
        for (int r = 0; r < 4; ++r) st[r] = f2b(o[dn][r] * inv);
        *(u16x4*)&aout[row * 768 + h * 64 + dn * 16 + lg * 4] = st;
    }
}

// ---------------------------------------------------------------- launch
extern "C" void kernel_launch(void* const* d_in, const int* in_sizes, int n_in,
                              void* d_out, int out_size, void* d_ws, size_t ws_size,
                              hipStream_t stream) {
    const float* x      = (const float*)d_in[0];
    const float* w_attn = (const float*)d_in[1];
    const float* b_attn = (const float*)d_in[2];
    const float* w_proj = (const float*)d_in[3];
    const float* b_proj = (const float*)d_in[4];
    float* out = (float*)d_out;
    char* ws = (char*)d_ws;

    u16* xb      = (u16*)(ws + 0);          // 8192*768   bf16 = 12,582,912 B
    u16* wTa     = (u16*)(ws + 12582912);   // 2304*768   bf16 =  3,538,944 B
    u16* wTp     = (u16*)(ws + 16121856);   //  768*768   bf16 =  1,179,648 B
    u16* qkv     = (u16*)(ws + 17301504);   // 8192*2304  bf16 = 37,748,736 B
    u16* vt      = (u16*)(ws + 55050240);   // 48*64*2048 bf16 = 12,582,912 B
    u16* aout    = (u16*)(ws + 67633152);   // 8192*768   bf16 = 12,582,912 B
    // ts buffer reuses the xb region (xb's last consumer is gemm1, which runs earlier)
    float* ts_raw = (float*)(ws + 0);       // 48*32*64 f32 = 393,216 B (aliases xb)

    convx_kernel<<<dim3(2048), dim3(256), 0, stream>>>(x, xb, 8192 * 768 / 4);
    wtrans2_kernel<<<dim3(96, 24), dim3(32, 8), 0, stream>>>(w_attn, w_proj, wTa, wTp);
    gemm_kernel<true><<<dim3(18, 64), dim3(256), 0, stream>>>(xb, wTa, b_attn,
                                                              (void*)qkv, 8192, 2304, 768);
    vtrans_kernel<<<dim3(32, 48), dim3(256), 0, stream>>>(qkv, vt, ts_raw);
    attn_kernel<<<dim3(48, 32), dim3(256), 0, stream>>>(qkv, vt, ts_raw, aout);
    gemm_kernel<false><<<dim3(6, 64), dim3(256), 0, stream>>>(aout, wTp, b_proj,
                                                              (void*)out, 8192, 768, 768);
}